// Round 13
// baseline (295.377 us; speedup 1.0000x reference)
//
#include <hip/hip_runtime.h>
#include <cstdint>
#include <cmath>

#define BATCH 65536
#define NREAL 246
#define NPAD  256
#define K1    784
#define K1PAD 832
#define BINS  100
#define ALPHA 0.1f
#define RB    32
#define NBLK  (BATCH/RB)     // 2048

typedef __bf16 bf16x8 __attribute__((ext_vector_type(8)));
typedef __bf16 bf16x4 __attribute__((ext_vector_type(4)));
typedef float  f32x4  __attribute__((ext_vector_type(4)));

// LDS layout (bytes)
#define OFF_HS     0         // 32 rows * 512B = 16384
#define OFF_STAGE  16384     // L1 stage dbuf 2*4096 = 8192 (union with hist)
#define OFF_HIST   16384     // 4 waves * 800 bins * 4B = 12800
#define OFF_MN     29184     // 32 rows * 4 waves * 4B = 512
#define OFF_MX     29696     // 512
#define OFF_LUT    30208     // 247 * 4B -> 1024
#define OFF_WENT   31232     // 4 waves * 6 layers * 4B -> 128
#define LDS_TOTAL  31360

// ---------------- weight/bias pad/convert ----------------
__global__ __launch_bounds__(256)
void pad_weights(const float* __restrict__ W1, const float* __restrict__ W2,
                 const float* __restrict__ W3, const float* __restrict__ W4,
                 const float* __restrict__ W5, const float* __restrict__ W6,
                 const float* __restrict__ W7,
                 const float* __restrict__ b1, const float* __restrict__ b2,
                 const float* __restrict__ b3, const float* __restrict__ b4,
                 const float* __restrict__ b5, const float* __restrict__ b6,
                 __bf16* __restrict__ W1p, __bf16* __restrict__ Wp,
                 __bf16* __restrict__ W7p, float* __restrict__ bpad)
{
    int tid = blockIdx.x * 256 + threadIdx.x;
    const int n1 = NPAD * K1PAD;        // 212992
    const int n2 = 5 * NPAD * NPAD;     // 327680
    const int n3 = 16 * NPAD;           // 4096
    if (tid < n1) {
        int row = tid / K1PAD;
        int k   = tid - row * K1PAD;
        W1p[tid] = (__bf16)((row < NREAL && k < K1) ? W1[row * K1 + k] : 0.0f);
    } else if (tid < n1 + n2) {
        int t = tid - n1;
        int wsel = t >> 16;
        int idx  = t & 65535;
        int row  = idx >> 8, k = idx & 255;
        const float* W = (wsel == 0) ? W2 : (wsel == 1) ? W3 : (wsel == 2) ? W4
                        : (wsel == 3) ? W5 : W6;
        Wp[t] = (__bf16)((row < NREAL && k < NREAL) ? W[row * NREAL + k] : 0.0f);
    } else if (tid < n1 + n2 + n3) {
        int t = tid - n1 - n2;
        int row = t >> 8, k = t & 255;
        W7p[t] = (__bf16)((row < 10 && k < NREAL) ? W7[row * NREAL + k] : 0.0f);
    } else if (tid < n1 + n2 + n3 + 6 * NPAD) {
        int t = tid - n1 - n2 - n3;
        int li = t >> 8, k = t & 255;
        const float* b = (li == 0) ? b1 : (li == 1) ? b2 : (li == 2) ? b3
                        : (li == 3) ? b4 : (li == 4) ? b5 : b6;
        bpad[t] = (k < NREAL) ? b[k] : 0.0f;
    }
}

// ---------------- megakernel: 4 waves, 32 rows/block, entropy fused into next GEMM ----------------
__global__ __launch_bounds__(256)
void mega(const float* __restrict__ x,
          const __bf16* __restrict__ W1p,
          const __bf16* __restrict__ Wp,
          const __bf16* __restrict__ W7p,
          const float* __restrict__ bpad,
          const float* __restrict__ b7,
          float* __restrict__ out, float* __restrict__ partial)
{
    __shared__ char smem[LDS_TOTAL];
    char*  Hb    = smem + OFF_HS;
    float* rowmn = (float*)(smem + OFF_MN);
    float* rowmx = (float*)(smem + OFF_MX);
    float* lut   = (float*)(smem + OFF_LUT);
    float* went  = (float*)(smem + OFF_WENT);
    int*   hist  = (int*)(smem + OFF_HIST);

    const int tid = threadIdx.x;
    const int w = tid >> 6, l = tid & 63;
    const int lane16 = l & 15, lane4 = l >> 4;
    const int m0 = blockIdx.x * RB;

    // entropy lane mapping: wave-private rows w*8..w*8+7
    const int rg = l >> 3, q = l & 7;
    const int erow = w * 8 + rg;
    const int eswz = (erow & 7) << 4;
    int* histW = hist + w * 800;

    if (tid < 247) lut[tid] = (tid > 0) ? (float)tid * logf((float)tid) : 0.0f;

    f32x4 acc[2][4];
#pragma unroll
    for (int i = 0; i < 2; ++i)
#pragma unroll
        for (int j = 0; j < 4; ++j) acc[i][j] = f32x4{0.f, 0.f, 0.f, 0.f};

    bf16x8 Bq[3][4];     // 3-slot ring, depth-2 prefetch (48 VGPRs)

    auto loadBq = [&](int s, const __bf16* Bbase, int hh) {
        const __bf16* pp = Bbase + (size_t)(w * 64 + lane16) * NPAD + (hh >> 1) * 64 + (hh & 1) * 32 + lane4 * 8;
#pragma unroll
        for (int j = 0; j < 4; ++j)
            Bq[s][j] = *(const bf16x8*)(pp + (size_t)j * 16 * NPAD);
    };

    // bias + leaky, packed b64 Hs write, minmax over bf16-rounded values
    auto epilogue = [&](const float* bp) {
        f32x4 bq[4];
#pragma unroll
        for (int j = 0; j < 4; ++j)
            bq[j] = *(const f32x4*)(bp + w * 64 + j * 16 + lane4 * 4);
#pragma unroll
        for (int i = 0; i < 2; ++i) {
            const int m = i * 16 + lane16;
            const int swz = (m & 7) << 4;
            float mn = 1e30f, mx = -1e30f;
#pragma unroll
            for (int j = 0; j < 4; ++j) {
                const int nbase = w * 64 + j * 16 + lane4 * 4;
                bf16x4 hv;
#pragma unroll
                for (int r = 0; r < 4; ++r) {
                    float v = acc[i][j][r] + bq[j][r];
                    v = v > 0.0f ? v : ALPHA * v;
                    bool valid = (nbase + r) < NREAL;
                    hv[r] = valid ? (__bf16)v : (__bf16)0.0f;
                    float vb = (float)hv[r];          // bin on bf16-rounded values
                    mn = fminf(mn, valid ? vb : 1e30f);
                    mx = fmaxf(mx, valid ? vb : -1e30f);
                }
                *(bf16x4*)(Hb + m * 512 + ((nbase * 2) ^ swz)) = hv;
            }
            mn = fminf(mn, __shfl_xor(mn, 16, 64));
            mx = fmaxf(mx, __shfl_xor(mx, 16, 64));
            mn = fminf(mn, __shfl_xor(mn, 32, 64));
            mx = fmaxf(mx, __shfl_xor(mx, 32, 64));
            if (lane4 == 0) { rowmn[m * 4 + w] = mn; rowmx[m * 4 + w] = mx; }
        }
    };

    auto esum = [&](int li) {
        float S = 0.0f;
        const int* hrow = histW + rg * 100;
#pragma unroll
        for (int t = 0; t < 13; ++t) {
            int b = q * 13 + t;
            if (b < 100) S += lut[hrow[b]];
        }
#pragma unroll
        for (int off = 1; off < 64; off <<= 1) S += __shfl_xor(S, off, 64);
        if (l == 0) went[w * 6 + li] = 8.0f * logf(246.0f) - S * (1.0f / 246.0f);
    };

    // ================= layer 1: K=784 streamed from HBM via reg-relay stage =================
    {
        const int srow = tid >> 3;        // 0..31
        const int skc  = (tid & 7) * 8;
        float4 xr0, xr1;
        auto issueX = [&](int kt) {
            int k0 = kt * 64 + skc;
            if (k0 < K1) {
                const float* gx = x + (size_t)(m0 + srow) * K1 + k0;
                xr0 = *(const float4*)gx;
                xr1 = *(const float4*)(gx + 4);
            } else {
                xr0 = float4{0.f,0.f,0.f,0.f};
                xr1 = float4{0.f,0.f,0.f,0.f};
            }
        };
        auto writeX = [&](int buf) {
            bf16x8 h;
            h[0]=(__bf16)xr0.x; h[1]=(__bf16)xr0.y; h[2]=(__bf16)xr0.z; h[3]=(__bf16)xr0.w;
            h[4]=(__bf16)xr1.x; h[5]=(__bf16)xr1.y; h[6]=(__bf16)xr1.z; h[7]=(__bf16)xr1.w;
            char* st = smem + OFF_STAGE + buf * 4096;
            *(bf16x8*)(st + srow * 128 + ((skc * 2) ^ ((srow & 7) << 4))) = h;
        };
        auto lB = [&](bf16x8 (&dst)[4], int kt, int kk) {
            const __bf16* p = W1p + (size_t)(w * 64 + lane16) * K1PAD + kt * 64 + kk * 32 + lane4 * 8;
#pragma unroll
            for (int j = 0; j < 4; ++j)
                dst[j] = *(const bf16x8*)(p + (size_t)j * 16 * K1PAD);
        };
        auto cH = [&](const char* st, int kbyte, const bf16x8 (&bfr)[4]) {
#pragma unroll
            for (int i = 0; i < 2; ++i) {
                int m = i * 16 + lane16;
                bf16x8 af = *(const bf16x8*)(st + m * 128 + ((kbyte + lane4 * 16) ^ ((m & 7) << 4)));
                __builtin_amdgcn_s_setprio(1);
#pragma unroll
                for (int j = 0; j < 4; ++j)
                    acc[i][j] = __builtin_amdgcn_mfma_f32_16x16x32_bf16(bfr[j], af, acc[i][j], 0, 0, 0);
                __builtin_amdgcn_s_setprio(0);
            }
        };

        bf16x8 curB[4], nxtB[4];
        issueX(0); writeX(0); issueX(1);
        lB(curB, 0, 0);
        for (int kt = 0; kt < 13; ++kt) {
            __syncthreads();
            if (kt < 12) { writeX((kt + 1) & 1); if (kt < 11) issueX(kt + 2); }
            const char* st = smem + OFF_STAGE + (kt & 1) * 4096;
            lB(nxtB, kt, 1);
            cH(st, 0, curB);
            if (kt < 12) lB(curB, kt + 1, 0);
            cH(st, 64, nxtB);
        }
    }

    // bootstrap Bq ring for layer-2 (drains at the barrier; values ready after)
    loadBq(0, Wp, 0);
    loadBq(1, Wp, 1);
    epilogue(bpad);             // layer-1 bias; writes Hs(1) + minmax
    __syncthreads();            // Hs(1) visible; stage region dead -> hist usable

    // ================= phases p=0..4: entropy(Hs(p+1)) fused with GEMM W(p+2) =================
    for (int p = 0; p < 5; ++p) {
        const __bf16* WpP = Wp + (size_t)p * (NPAD * NPAD);
        const __bf16* WpN = WpP + NPAD * NPAD;

#pragma unroll
        for (int i = 0; i < 2; ++i)
#pragma unroll
            for (int j = 0; j < 4; ++j) acc[i][j] = f32x4{0.f, 0.f, 0.f, 0.f};

        // zero wave-private hist (no cross-wave sync needed anywhere in entropy)
#pragma unroll
        for (int t = 0; t < 13; ++t) { int b = t * 64 + l; if (b < 800) histW[b] = 0; }
        // per-row min/max for this wave's entropy rows
        f32x4 m4 = *(const f32x4*)(rowmn + erow * 4);
        f32x4 x4 = *(const f32x4*)(rowmx + erow * 4);
        float emn = fminf(fminf(m4[0], m4[1]), fminf(m4[2], m4[3]));
        float emx = fmaxf(fmaxf(x4[0], x4[1]), fmaxf(x4[2], x4[3]));
        float ers = (emx > emn) ? 100.0f / (emx - emn) : 0.0f;
        asm volatile("s_waitcnt lgkmcnt(0)" ::: "memory");   // hist zeros landed (wave-private)

        // fused: 8 x { B-prefetch + 2 ds_read + 8 MFMA + entropy slice }
#pragma unroll
        for (int h = 0; h < 8; ++h) {
            if (h < 6)      loadBq((h + 2) % 3, WpP, h + 2);
            else if (p < 4) loadBq(h - 6, WpN, h - 6);       // next layer h0/h1 -> slots 0/1
            // GEMM A fragments + MFMA
#pragma unroll
            for (int i = 0; i < 2; ++i) {
                int m = i * 16 + lane16;
                bf16x8 af = *(const bf16x8*)(Hb + m * 512 + ((h * 64 + lane4 * 16) ^ ((m & 7) << 4)));
                __builtin_amdgcn_s_setprio(1);
#pragma unroll
                for (int j = 0; j < 4; ++j)
                    acc[i][j] = __builtin_amdgcn_mfma_f32_16x16x32_bf16(Bq[h % 3][j], af, acc[i][j], 0, 0, 0);
                __builtin_amdgcn_s_setprio(0);
            }
            // entropy slice h: 4 cols of this lane's row
            {
                int c0 = q * 32 + h * 4;
                bf16x4 hv = *(const bf16x4*)(Hb + erow * 512 + ((c0 * 2) ^ eswz));
#pragma unroll
                for (int e = 0; e < 4; ++e) {
                    if (c0 + e < NREAL) {
                        int idx = (int)floorf(((float)hv[e] - emn) * ers);
                        idx = idx < 0 ? 0 : (idx > BINS - 1 ? BINS - 1 : idx);
                        atomicAdd(&histW[rg * 100 + idx], 1);
                    }
                }
            }
        }
        asm volatile("s_waitcnt lgkmcnt(0)" ::: "memory");   // own atomics done
        esum(p);

        __syncthreads();            // all waves done reading Hs(p+1)
        epilogue(bpad + (size_t)(p + 1) * NPAD);
        __syncthreads();            // Hs(p+2) + minmax visible
    }

    // ================= tail: entropy(Hs(6)) standalone =================
    {
#pragma unroll
        for (int t = 0; t < 13; ++t) { int b = t * 64 + l; if (b < 800) histW[b] = 0; }
        f32x4 m4 = *(const f32x4*)(rowmn + erow * 4);
        f32x4 x4 = *(const f32x4*)(rowmx + erow * 4);
        float emn = fminf(fminf(m4[0], m4[1]), fminf(m4[2], m4[3]));
        float emx = fmaxf(fmaxf(x4[0], x4[1]), fmaxf(x4[2], x4[3]));
        float ers = (emx > emn) ? 100.0f / (emx - emn) : 0.0f;
        asm volatile("s_waitcnt lgkmcnt(0)" ::: "memory");
#pragma unroll
        for (int h = 0; h < 8; ++h) {
            int c0 = q * 32 + h * 4;
            bf16x4 hv = *(const bf16x4*)(Hb + erow * 512 + ((c0 * 2) ^ eswz));
#pragma unroll
            for (int e = 0; e < 4; ++e) {
                if (c0 + e < NREAL) {
                    int idx = (int)floorf(((float)hv[e] - emn) * ers);
                    idx = idx < 0 ? 0 : (idx > BINS - 1 ? BINS - 1 : idx);
                    atomicAdd(&histW[rg * 100 + idx], 1);
                }
            }
        }
        asm volatile("s_waitcnt lgkmcnt(0)" ::: "memory");
        esum(5);
    }

    // ================= head: waves 0..1, one 16-row MFMA strip each =================
    if (w < 2) {
        f32x4 hacc = f32x4{0.f, 0.f, 0.f, 0.f};
        int row = w * 16 + lane16;
#pragma unroll
        for (int kt = 0; kt < 8; ++kt) {
            bf16x8 af = *(const bf16x8*)(Hb + row * 512 + ((kt * 64 + lane4 * 16) ^ ((row & 7) << 4)));
            bf16x8 bf = *(const bf16x8*)(W7p + (size_t)lane16 * NPAD + kt * 32 + lane4 * 8);
            hacc = __builtin_amdgcn_mfma_f32_16x16x32_bf16(af, bf, hacc, 0, 0, 0);
        }
        float bv = (lane16 < 10) ? b7[lane16] : 0.0f;
#pragma unroll
        for (int r = 0; r < 4; ++r) {
            float lg = fmaxf(hacc[r] + bv, 0.0f);
            float vm = (lane16 < 10) ? lg : -1e30f;
#pragma unroll
            for (int off = 8; off; off >>= 1) vm = fmaxf(vm, __shfl_xor(vm, off, 64));
            float ex = (lane16 < 10) ? expf(lg - vm) : 0.0f;
#pragma unroll
            for (int off = 8; off; off >>= 1) ex += __shfl_xor(ex, off, 64);
            float ls = vm + logf(ex);
            if (lane16 < 10) {
                int grow = m0 + w * 16 + lane4 * 4 + r;
                out[(size_t)grow * 10 + lane16] = lg - ls;
            }
        }
    }

    __syncthreads();
    if (tid < 6) {
        float s = went[tid] + went[6 + tid] + went[12 + tid] + went[18 + tid];
        partial[tid * NBLK + blockIdx.x] = s;
    }
}

// ---------------- final entropy mean (deterministic fixed-order) ----------------
__global__ __launch_bounds__(256)
void reduce_kernel(const float* __restrict__ partial, float* __restrict__ out)
{
    __shared__ float s[256];
    const int li = blockIdx.x, tid = threadIdx.x;
    float a = 0.0f;
    for (int i = tid; i < NBLK; i += 256) a += partial[li * NBLK + i];
    s[tid] = a;
    __syncthreads();
    for (int st = 128; st; st >>= 1) {
        if (tid < st) s[tid] += s[tid + st];
        __syncthreads();
    }
    if (tid == 0)
        out[(size_t)BATCH * 10 + li] = s[0] / (float)BATCH + logf((float)BINS);
}

// ---------------- launch ----------------
extern "C" void kernel_launch(void* const* d_in, const int* in_sizes, int n_in,
                              void* d_out, int out_size, void* d_ws, size_t ws_size,
                              hipStream_t stream)
{
    (void)in_sizes; (void)n_in; (void)out_size; (void)ws_size;

    const float* x  = (const float*)d_in[0];
    const float* W1 = (const float*)d_in[1];
    const float* b1 = (const float*)d_in[2];
    const float* W2 = (const float*)d_in[3];
    const float* b2 = (const float*)d_in[4];
    const float* W3 = (const float*)d_in[5];
    const float* b3 = (const float*)d_in[6];
    const float* W4 = (const float*)d_in[7];
    const float* b4 = (const float*)d_in[8];
    const float* W5 = (const float*)d_in[9];
    const float* b5 = (const float*)d_in[10];
    const float* W6 = (const float*)d_in[11];
    const float* b6 = (const float*)d_in[12];
    const float* W7 = (const float*)d_in[13];
    const float* b7 = (const float*)d_in[14];

    char* ws = (char*)d_ws;
    // ws layout (bytes):
    //   0       : W1p  256*832 bf16   = 425984
    //   425984  : Wp   5*256*256 bf16 = 655360
    //   1081344 : W7p  16*256 bf16    = 8192
    //   1089536 : bpad 6*256 f32      = 6144
    //   1095680 : partial 6*2048 f32  = 49152
    __bf16* W1p = (__bf16*)(ws);
    __bf16* Wp  = (__bf16*)(ws + 425984);
    __bf16* W7p = (__bf16*)(ws + 1081344);
    float*  bpad = (float*)(ws + 1089536);
    float*  partial = (float*)(ws + 1095680);
    float*  out = (float*)d_out;

    pad_weights<<<2134, 256, 0, stream>>>(W1, W2, W3, W4, W5, W6, W7,
                                          b1, b2, b3, b4, b5, b6,
                                          W1p, Wp, W7p, bpad);
    mega<<<NBLK, 256, 0, stream>>>(x, W1p, Wp, W7p, bpad, b7, out, partial);
    reduce_kernel<<<6, 256, 0, stream>>>(partial, out);
}

// Round 14
// 293.150 us; speedup vs baseline: 1.0076x; 1.0076x over previous
//
#include <hip/hip_runtime.h>
#include <cstdint>
#include <cmath>

#define BATCH 65536
#define NREAL 246
#define NPAD  256
#define K1    784
#define K1PAD 832
#define BINS  100
#define ALPHA 0.1f
#define RB    32
#define NBLK  (BATCH/RB)     // 2048

typedef __bf16 bf16x8 __attribute__((ext_vector_type(8)));
typedef __bf16 bf16x4 __attribute__((ext_vector_type(4)));
typedef float  f32x4  __attribute__((ext_vector_type(4)));

// LDS layout (bytes)
#define OFF_HS     0         // 32 rows * 512B = 16384
#define OFF_STAGE  16384     // L1 stage dbuf 2*4096 = 8192 (union with hist)
#define OFF_HIST   16384     // 4 waves * 800 bins * 4B = 12800
#define OFF_MN     29184     // 32 rows * 4 waves * 4B = 512
#define OFF_MX     29696     // 512
#define OFF_WENT   30208     // 4 waves * 6 layers * 4B -> 128
#define LDS_TOTAL  30336     // ~30 KB -> 5 blocks/CU by LDS; target 4 by regs

// ---------------- weight/bias pad/convert ----------------
__global__ __launch_bounds__(256)
void pad_weights(const float* __restrict__ W1, const float* __restrict__ W2,
                 const float* __restrict__ W3, const float* __restrict__ W4,
                 const float* __restrict__ W5, const float* __restrict__ W6,
                 const float* __restrict__ W7,
                 const float* __restrict__ b1, const float* __restrict__ b2,
                 const float* __restrict__ b3, const float* __restrict__ b4,
                 const float* __restrict__ b5, const float* __restrict__ b6,
                 __bf16* __restrict__ W1p, __bf16* __restrict__ Wp,
                 __bf16* __restrict__ W7p, float* __restrict__ bpad)
{
    int tid = blockIdx.x * 256 + threadIdx.x;
    const int n1 = NPAD * K1PAD;        // 212992
    const int n2 = 5 * NPAD * NPAD;     // 327680
    const int n3 = 16 * NPAD;           // 4096
    if (tid < n1) {
        int row = tid / K1PAD;
        int k   = tid - row * K1PAD;
        W1p[tid] = (__bf16)((row < NREAL && k < K1) ? W1[row * K1 + k] : 0.0f);
    } else if (tid < n1 + n2) {
        int t = tid - n1;
        int wsel = t >> 16;
        int idx  = t & 65535;
        int row  = idx >> 8, k = idx & 255;
        const float* W = (wsel == 0) ? W2 : (wsel == 1) ? W3 : (wsel == 2) ? W4
                        : (wsel == 3) ? W5 : W6;
        Wp[t] = (__bf16)((row < NREAL && k < NREAL) ? W[row * NREAL + k] : 0.0f);
    } else if (tid < n1 + n2 + n3) {
        int t = tid - n1 - n2;
        int row = t >> 8, k = t & 255;
        W7p[t] = (__bf16)((row < 10 && k < NREAL) ? W7[row * NREAL + k] : 0.0f);
    } else if (tid < n1 + n2 + n3 + 6 * NPAD) {
        int t = tid - n1 - n2 - n3;
        int li = t >> 8, k = t & 255;
        const float* b = (li == 0) ? b1 : (li == 1) ? b2 : (li == 2) ? b3
                        : (li == 3) ? b4 : (li == 4) ? b5 : b6;
        bpad[t] = (k < NREAL) ? b[k] : 0.0f;
    }
}

// ---------------- megakernel: 4 waves, 32 rows/block, <=128 regs target ----------------
__global__ __launch_bounds__(256)
void mega(const float* __restrict__ x,
          const __bf16* __restrict__ W1p,
          const __bf16* __restrict__ Wp,
          const __bf16* __restrict__ W7p,
          const float* __restrict__ bpad,
          const float* __restrict__ b7,
          float* __restrict__ out, float* __restrict__ partial)
{
    __shared__ char smem[LDS_TOTAL];
    char*  Hb    = smem + OFF_HS;
    float* rowmn = (float*)(smem + OFF_MN);
    float* rowmx = (float*)(smem + OFF_MX);
    float* went  = (float*)(smem + OFF_WENT);
    int*   hist  = (int*)(smem + OFF_HIST);

    const int tid = threadIdx.x;
    const int w = tid >> 6, l = tid & 63;
    const int lane16 = l & 15, lane4 = l >> 4;
    const int m0 = blockIdx.x * RB;

    // entropy lane mapping: wave-private rows w*8..w*8+7
    const int rg = l >> 3, q = l & 7;
    const int erow = w * 8 + rg;
    const int eswz = (erow & 7) << 4;
    int* histW = hist + w * 800;

    f32x4 acc[2][4];
#pragma unroll
    for (int i = 0; i < 2; ++i)
#pragma unroll
        for (int j = 0; j < 4; ++j) acc[i][j] = f32x4{0.f, 0.f, 0.f, 0.f};

    bf16x8 Bq[2][4];     // 2-slot ring (32 VGPRs), depth-2 issue-to-use distance

    auto loadBq = [&](int s, const __bf16* Bbase, int hh) {
        const __bf16* pp = Bbase + (size_t)(w * 64 + lane16) * NPAD + (hh >> 1) * 64 + (hh & 1) * 32 + lane4 * 8;
#pragma unroll
        for (int j = 0; j < 4; ++j)
            Bq[s][j] = *(const bf16x8*)(pp + (size_t)j * 16 * NPAD);
    };

    // bias + leaky, packed b64 Hs write, minmax over bf16-rounded values
    auto epilogue = [&](const float* bp) {
        f32x4 bq[4];
#pragma unroll
        for (int j = 0; j < 4; ++j)
            bq[j] = *(const f32x4*)(bp + w * 64 + j * 16 + lane4 * 4);
#pragma unroll
        for (int i = 0; i < 2; ++i) {
            const int m = i * 16 + lane16;
            const int swz = (m & 7) << 4;
            float mn = 1e30f, mx = -1e30f;
#pragma unroll
            for (int j = 0; j < 4; ++j) {
                const int nbase = w * 64 + j * 16 + lane4 * 4;
                bf16x4 hv;
#pragma unroll
                for (int r = 0; r < 4; ++r) {
                    float v = acc[i][j][r] + bq[j][r];
                    v = v > 0.0f ? v : ALPHA * v;
                    bool valid = (nbase + r) < NREAL;
                    hv[r] = valid ? (__bf16)v : (__bf16)0.0f;
                    float vb = (float)hv[r];          // bin on bf16-rounded values
                    mn = fminf(mn, valid ? vb : 1e30f);
                    mx = fmaxf(mx, valid ? vb : -1e30f);
                }
                *(bf16x4*)(Hb + m * 512 + ((nbase * 2) ^ swz)) = hv;
            }
            mn = fminf(mn, __shfl_xor(mn, 16, 64));
            mx = fmaxf(mx, __shfl_xor(mx, 16, 64));
            mn = fminf(mn, __shfl_xor(mn, 32, 64));
            mx = fmaxf(mx, __shfl_xor(mx, 32, 64));
            if (lane4 == 0) { rowmn[m * 4 + w] = mn; rowmx[m * 4 + w] = mx; }
        }
    };

    // esum: direct c*ln(c) via v_log (no LDS LUT, no chained LDS reads)
    auto esum = [&](int li) {
        const int* hrow = histW + rg * 100;
        float S = 0.0f;
#pragma unroll
        for (int t = 0; t < 13; ++t) {
            int b = q * 13 + t;
            if (b < 100) {
                float f = (float)hrow[b];
                float g = fmaxf(f, 1.0f);     // ln(max(c,1)): c=0 -> 0*0 = 0
                S = fmaf(f, __logf(g), S);
            }
        }
#pragma unroll
        for (int off = 1; off < 64; off <<= 1) S += __shfl_xor(S, off, 64);
        if (l == 0) went[w * 6 + li] = 8.0f * logf(246.0f) - S * (1.0f / 246.0f);
    };

    // ================= layer 1: K=784 streamed from HBM via reg-relay stage =================
    {
        const int srow = tid >> 3;        // 0..31
        const int skc  = (tid & 7) * 8;
        float4 xr0, xr1;
        auto issueX = [&](int kt) {
            int k0 = kt * 64 + skc;
            if (k0 < K1) {
                const float* gx = x + (size_t)(m0 + srow) * K1 + k0;
                xr0 = *(const float4*)gx;
                xr1 = *(const float4*)(gx + 4);
            } else {
                xr0 = float4{0.f,0.f,0.f,0.f};
                xr1 = float4{0.f,0.f,0.f,0.f};
            }
        };
        auto writeX = [&](int buf) {
            bf16x8 h;
            h[0]=(__bf16)xr0.x; h[1]=(__bf16)xr0.y; h[2]=(__bf16)xr0.z; h[3]=(__bf16)xr0.w;
            h[4]=(__bf16)xr1.x; h[5]=(__bf16)xr1.y; h[6]=(__bf16)xr1.z; h[7]=(__bf16)xr1.w;
            char* st = smem + OFF_STAGE + buf * 4096;
            *(bf16x8*)(st + srow * 128 + ((skc * 2) ^ ((srow & 7) << 4))) = h;
        };
        auto lB = [&](int s, int kt, int kk) {
            const __bf16* p = W1p + (size_t)(w * 64 + lane16) * K1PAD + kt * 64 + kk * 32 + lane4 * 8;
#pragma unroll
            for (int j = 0; j < 4; ++j)
                Bq[s][j] = *(const bf16x8*)(p + (size_t)j * 16 * K1PAD);
        };
        auto cH = [&](const char* st, int kbyte, int s) {
#pragma unroll
            for (int i = 0; i < 2; ++i) {
                int m = i * 16 + lane16;
                bf16x8 af = *(const bf16x8*)(st + m * 128 + ((kbyte + lane4 * 16) ^ ((m & 7) << 4)));
                __builtin_amdgcn_s_setprio(1);
#pragma unroll
                for (int j = 0; j < 4; ++j)
                    acc[i][j] = __builtin_amdgcn_mfma_f32_16x16x32_bf16(s ? Bq[1][j] : Bq[0][j], af, acc[i][j], 0, 0, 0);
                __builtin_amdgcn_s_setprio(0);
            }
        };

        issueX(0); writeX(0); issueX(1);
        lB(0, 0, 0);
        for (int kt = 0; kt < 13; ++kt) {
            __syncthreads();
            if (kt < 12) { writeX((kt + 1) & 1); if (kt < 11) issueX(kt + 2); }
            const char* st = smem + OFF_STAGE + (kt & 1) * 4096;
            lB(1, kt, 1);
            cH(st, 0, 0);
            if (kt < 12) lB(0, kt + 1, 0);
            cH(st, 64, 1);
        }
    }

    // bootstrap Bq for layer-2 (in flight during epilogue + barrier)
    loadBq(0, Wp, 0);
    loadBq(1, Wp, 1);
    epilogue(bpad);             // layer-1 bias; writes Hs(1) + minmax
    __syncthreads();            // Hs(1) visible; stage region dead -> hist usable

    // ================= phases p=0..4: entropy(Hs(p+1)) fused with GEMM W(p+2) =================
    for (int p = 0; p < 5; ++p) {
        const __bf16* WpP = Wp + (size_t)p * (NPAD * NPAD);
        const __bf16* WpN = WpP + NPAD * NPAD;

#pragma unroll
        for (int i = 0; i < 2; ++i)
#pragma unroll
            for (int j = 0; j < 4; ++j) acc[i][j] = f32x4{0.f, 0.f, 0.f, 0.f};

        // zero wave-private hist
#pragma unroll
        for (int t = 0; t < 13; ++t) { int b = t * 64 + l; if (b < 800) histW[b] = 0; }
        // per-row min/max for this wave's entropy rows
        f32x4 m4 = *(const f32x4*)(rowmn + erow * 4);
        f32x4 x4 = *(const f32x4*)(rowmx + erow * 4);
        float emn = fminf(fminf(m4[0], m4[1]), fminf(m4[2], m4[3]));
        float emx = fmaxf(fmaxf(x4[0], x4[1]), fmaxf(x4[2], x4[3]));
        float ers = (emx > emn) ? 100.0f / (emx - emn) : 0.0f;
        float eb  = -emn * ers;
        asm volatile("s_waitcnt lgkmcnt(0)" ::: "memory");   // hist zeros landed (wave-private)

        // fused: 8 x { 2 ds_read + 8 MFMA + B-prefetch + entropy slice }
#pragma unroll
        for (int h = 0; h < 8; ++h) {
#pragma unroll
            for (int i = 0; i < 2; ++i) {
                int m = i * 16 + lane16;
                bf16x8 af = *(const bf16x8*)(Hb + m * 512 + ((h * 64 + lane4 * 16) ^ ((m & 7) << 4)));
                __builtin_amdgcn_s_setprio(1);
#pragma unroll
                for (int j = 0; j < 4; ++j)
                    acc[i][j] = __builtin_amdgcn_mfma_f32_16x16x32_bf16((h & 1) ? Bq[1][j] : Bq[0][j],
                                                                        af, acc[i][j], 0, 0, 0);
                __builtin_amdgcn_s_setprio(0);
            }
            // prefetch into the slot just consumed (ready at h+2)
            if (h < 6)      loadBq(h & 1, WpP, h + 2);
            else if (p < 4) loadBq(h & 1, WpN, h - 6);
            // entropy slice h: 4 cols of this lane's row
            {
                int c0 = q * 32 + h * 4;
                bf16x4 hv = *(const bf16x4*)(Hb + erow * 512 + ((c0 * 2) ^ eswz));
#pragma unroll
                for (int e = 0; e < 4; ++e) {
                    if (c0 + e < NREAL) {
                        int idx = (int)fmaf((float)hv[e], ers, eb);   // trunc == floor (arg >= ~0)
                        idx = idx > BINS - 1 ? BINS - 1 : (idx < 0 ? 0 : idx);
                        atomicAdd(&histW[rg * 100 + idx], 1);
                    }
                }
            }
        }
        asm volatile("s_waitcnt lgkmcnt(0)" ::: "memory");   // own atomics done
        esum(p);

        __syncthreads();            // all waves done reading Hs(p+1)
        epilogue(bpad + (size_t)(p + 1) * NPAD);
        __syncthreads();            // Hs(p+2) + minmax visible
    }

    // ================= tail: entropy(Hs(6)) standalone =================
    {
#pragma unroll
        for (int t = 0; t < 13; ++t) { int b = t * 64 + l; if (b < 800) histW[b] = 0; }
        f32x4 m4 = *(const f32x4*)(rowmn + erow * 4);
        f32x4 x4 = *(const f32x4*)(rowmx + erow * 4);
        float emn = fminf(fminf(m4[0], m4[1]), fminf(m4[2], m4[3]));
        float emx = fmaxf(fmaxf(x4[0], x4[1]), fmaxf(x4[2], x4[3]));
        float ers = (emx > emn) ? 100.0f / (emx - emn) : 0.0f;
        float eb  = -emn * ers;
        asm volatile("s_waitcnt lgkmcnt(0)" ::: "memory");
#pragma unroll
        for (int h = 0; h < 8; ++h) {
            int c0 = q * 32 + h * 4;
            bf16x4 hv = *(const bf16x4*)(Hb + erow * 512 + ((c0 * 2) ^ eswz));
#pragma unroll
            for (int e = 0; e < 4; ++e) {
                if (c0 + e < NREAL) {
                    int idx = (int)fmaf((float)hv[e], ers, eb);
                    idx = idx > BINS - 1 ? BINS - 1 : (idx < 0 ? 0 : idx);
                    atomicAdd(&histW[rg * 100 + idx], 1);
                }
            }
        }
        asm volatile("s_waitcnt lgkmcnt(0)" ::: "memory");
        esum(5);
    }

    // ================= head: waves 0..1, one 16-row MFMA strip each =================
    if (w < 2) {
        f32x4 hacc = f32x4{0.f, 0.f, 0.f, 0.f};
        int row = w * 16 + lane16;
#pragma unroll
        for (int kt = 0; kt < 8; ++kt) {
            bf16x8 af = *(const bf16x8*)(Hb + row * 512 + ((kt * 64 + lane4 * 16) ^ ((row & 7) << 4)));
            bf16x8 bf = *(const bf16x8*)(W7p + (size_t)lane16 * NPAD + kt * 32 + lane4 * 8);
            hacc = __builtin_amdgcn_mfma_f32_16x16x32_bf16(af, bf, hacc, 0, 0, 0);
        }
        float bv = (lane16 < 10) ? b7[lane16] : 0.0f;
#pragma unroll
        for (int r = 0; r < 4; ++r) {
            float lg = fmaxf(hacc[r] + bv, 0.0f);
            float vm = (lane16 < 10) ? lg : -1e30f;
#pragma unroll
            for (int off = 8; off; off >>= 1) vm = fmaxf(vm, __shfl_xor(vm, off, 64));
            float ex = (lane16 < 10) ? expf(lg - vm) : 0.0f;
#pragma unroll
            for (int off = 8; off; off >>= 1) ex += __shfl_xor(ex, off, 64);
            float ls = vm + logf(ex);
            if (lane16 < 10) {
                int grow = m0 + w * 16 + lane4 * 4 + r;
                out[(size_t)grow * 10 + lane16] = lg - ls;
            }
        }
    }

    __syncthreads();
    if (tid < 6) {
        float s = went[tid] + went[6 + tid] + went[12 + tid] + went[18 + tid];
        partial[tid * NBLK + blockIdx.x] = s;
    }
}

// ---------------- final entropy mean (deterministic fixed-order) ----------------
__global__ __launch_bounds__(256)
void reduce_kernel(const float* __restrict__ partial, float* __restrict__ out)
{
    __shared__ float s[256];
    const int li = blockIdx.x, tid = threadIdx.x;
    float a = 0.0f;
    for (int i = tid; i < NBLK; i += 256) a += partial[li * NBLK + i];
    s[tid] = a;
    __syncthreads();
    for (int st = 128; st; st >>= 1) {
        if (tid < st) s[tid] += s[tid + st];
        __syncthreads();
    }
    if (tid == 0)
        out[(size_t)BATCH * 10 + li] = s[0] / (float)BATCH + logf((float)BINS);
}

// ---------------- launch ----------------
extern "C" void kernel_launch(void* const* d_in, const int* in_sizes, int n_in,
                              void* d_out, int out_size, void* d_ws, size_t ws_size,
                              hipStream_t stream)
{
    (void)in_sizes; (void)n_in; (void)out_size; (void)ws_size;

    const float* x  = (const float*)d_in[0];
    const float* W1 = (const float*)d_in[1];
    const float* b1 = (const float*)d_in[2];
    const float* W2 = (const float*)d_in[3];
    const float* b2 = (const float*)d_in[4];
    const float* W3 = (const float*)d_in[5];
    const float* b3 = (const float*)d_in[6];
    const float* W4 = (const float*)d_in[7];
    const float* b4 = (const float*)d_in[8];
    const float* W5 = (const float*)d_in[9];
    const float* b5 = (const float*)d_in[10];
    const float* W6 = (const float*)d_in[11];
    const float* b6 = (const float*)d_in[12];
    const float* W7 = (const float*)d_in[13];
    const float* b7 = (const float*)d_in[14];

    char* ws = (char*)d_ws;
    // ws layout (bytes):
    //   0       : W1p  256*832 bf16   = 425984
    //   425984  : Wp   5*256*256 bf16 = 655360
    //   1081344 : W7p  16*256 bf16    = 8192
    //   1089536 : bpad 6*256 f32      = 6144
    //   1095680 : partial 6*2048 f32  = 49152
    __bf16* W1p = (__bf16*)(ws);
    __bf16* Wp  = (__bf16*)(ws + 425984);
    __bf16* W7p = (__bf16*)(ws + 1081344);
    float*  bpad = (float*)(ws + 1089536);
    float*  partial = (float*)(ws + 1095680);
    float*  out = (float*)d_out;

    pad_weights<<<2134, 256, 0, stream>>>(W1, W2, W3, W4, W5, W6, W7,
                                          b1, b2, b3, b4, b5, b6,
                                          W1p, Wp, W7p, bpad);
    mega<<<NBLK, 256, 0, stream>>>(x, W1p, Wp, W7p, bpad, b7, out, partial);
    reduce_kernel<<<6, 256, 0, stream>>>(partial, out);
}

// Round 15
// 290.356 us; speedup vs baseline: 1.0173x; 1.0096x over previous
//
#include <hip/hip_runtime.h>
#include <cstdint>
#include <cmath>

#define BATCH 65536
#define NREAL 246
#define NPAD  256
#define K1    784
#define K1PAD 832
#define BINS  100
#define ALPHA 0.1f
#define RB    32
#define NBLK  (BATCH/RB)     // 2048

typedef __bf16 bf16x8 __attribute__((ext_vector_type(8)));
typedef __bf16 bf16x4 __attribute__((ext_vector_type(4)));
typedef __bf16 bf16x2 __attribute__((ext_vector_type(2)));
typedef float  f32x4  __attribute__((ext_vector_type(4)));

// LDS layout (bytes)
#define OFF_HS     0         // 32 rows * 512B = 16384
#define OFF_STAGE  16384     // L1 stage dbuf 2*4096 = 8192 (union with hist)
#define OFF_HIST   16384     // 8 waves * 400 bins * 4B = 12800
#define OFF_MN     29184     // 32 rows * 8 waves * 4B = 1024
#define OFF_MX     30208     // 1024
#define OFF_WENT   31232     // 8 waves * 6 layers * 4B = 192
#define LDS_TOTAL  31424

// ---------------- weight/bias pad/convert ----------------
__global__ __launch_bounds__(256)
void pad_weights(const float* __restrict__ W1, const float* __restrict__ W2,
                 const float* __restrict__ W3, const float* __restrict__ W4,
                 const float* __restrict__ W5, const float* __restrict__ W6,
                 const float* __restrict__ W7,
                 const float* __restrict__ b1, const float* __restrict__ b2,
                 const float* __restrict__ b3, const float* __restrict__ b4,
                 const float* __restrict__ b5, const float* __restrict__ b6,
                 __bf16* __restrict__ W1p, __bf16* __restrict__ Wp,
                 __bf16* __restrict__ W7p, float* __restrict__ bpad)
{
    int tid = blockIdx.x * 256 + threadIdx.x;
    const int n1 = NPAD * K1PAD;        // 212992
    const int n2 = 5 * NPAD * NPAD;     // 327680
    const int n3 = 16 * NPAD;           // 4096
    if (tid < n1) {
        int row = tid / K1PAD;
        int k   = tid - row * K1PAD;
        W1p[tid] = (__bf16)((row < NREAL && k < K1) ? W1[row * K1 + k] : 0.0f);
    } else if (tid < n1 + n2) {
        int t = tid - n1;
        int wsel = t >> 16;
        int idx  = t & 65535;
        int row  = idx >> 8, k = idx & 255;
        const float* W = (wsel == 0) ? W2 : (wsel == 1) ? W3 : (wsel == 2) ? W4
                        : (wsel == 3) ? W5 : W6;
        Wp[t] = (__bf16)((row < NREAL && k < NREAL) ? W[row * NREAL + k] : 0.0f);
    } else if (tid < n1 + n2 + n3) {
        int t = tid - n1 - n2;
        int row = t >> 8, k = t & 255;
        W7p[t] = (__bf16)((row < 10 && k < NREAL) ? W7[row * NREAL + k] : 0.0f);
    } else if (tid < n1 + n2 + n3 + 6 * NPAD) {
        int t = tid - n1 - n2 - n3;
        int li = t >> 8, k = t & 255;
        const float* b = (li == 0) ? b1 : (li == 1) ? b2 : (li == 2) ? b3
                        : (li == 3) ? b4 : (li == 4) ? b5 : b6;
        bpad[t] = (k < NREAL) ? b[k] : 0.0f;
    }
}

// ---------------- megakernel: 8 waves x (32r x 32c), acc=16 -> <=128-reg class ----------------
__global__ __launch_bounds__(512)
void mega(const float* __restrict__ x,
          const __bf16* __restrict__ W1p,
          const __bf16* __restrict__ Wp,
          const __bf16* __restrict__ W7p,
          const float* __restrict__ bpad,
          const float* __restrict__ b7,
          float* __restrict__ out, float* __restrict__ partial)
{
    __shared__ char smem[LDS_TOTAL];
    char*  Hb    = smem + OFF_HS;
    float* rowmn = (float*)(smem + OFF_MN);
    float* rowmx = (float*)(smem + OFF_MX);
    float* went  = (float*)(smem + OFF_WENT);
    int*   hist  = (int*)(smem + OFF_HIST);

    const int tid = threadIdx.x;
    const int w = tid >> 6, l = tid & 63;
    const int lane16 = l & 15, lane4 = l >> 4;
    const int wc = w * 32;               // wave's 32-col strip
    const int m0 = blockIdx.x * RB;

    // entropy mapping: wave-private rows w*4..w*4+3, 16 lanes per row
    const int rg = l >> 4, q = l & 15;
    const int erow = w * 4 + rg;
    const int eswz = (erow & 7) << 4;
    int* histW = hist + w * 400;

    f32x4 acc[2][2];
#pragma unroll
    for (int i = 0; i < 2; ++i)
#pragma unroll
        for (int j = 0; j < 2; ++j) acc[i][j] = f32x4{0.f, 0.f, 0.f, 0.f};

    bf16x8 Bq[2][2];     // 2-slot ring x 2 col-frags = 16 VGPRs

    auto loadBq = [&](int s, const __bf16* Bbase, int hh) {
        const __bf16* pp = Bbase + (size_t)(wc + lane16) * NPAD + hh * 32 + lane4 * 8;
#pragma unroll
        for (int j = 0; j < 2; ++j)
            Bq[s][j] = *(const bf16x8*)(pp + (size_t)j * 16 * NPAD);
    };

    // bias + leaky, packed b64 Hs write, minmax over bf16-rounded values
    auto epilogue = [&](const float* bp) {
        f32x4 bq[2];
#pragma unroll
        for (int j = 0; j < 2; ++j)
            bq[j] = *(const f32x4*)(bp + wc + j * 16 + lane4 * 4);
#pragma unroll
        for (int i = 0; i < 2; ++i) {
            const int m = i * 16 + lane16;
            const int swz = (m & 7) << 4;
            float mn = 1e30f, mx = -1e30f;
#pragma unroll
            for (int j = 0; j < 2; ++j) {
                const int nbase = wc + j * 16 + lane4 * 4;
                bf16x4 hv;
#pragma unroll
                for (int r = 0; r < 4; ++r) {
                    float v = acc[i][j][r] + bq[j][r];
                    v = v > 0.0f ? v : ALPHA * v;
                    bool valid = (nbase + r) < NREAL;
                    hv[r] = valid ? (__bf16)v : (__bf16)0.0f;
                    float vb = (float)hv[r];          // bin on bf16-rounded values
                    mn = fminf(mn, valid ? vb : 1e30f);
                    mx = fmaxf(mx, valid ? vb : -1e30f);
                }
                *(bf16x4*)(Hb + m * 512 + ((nbase * 2) ^ swz)) = hv;
            }
            mn = fminf(mn, __shfl_xor(mn, 16, 64));
            mx = fmaxf(mx, __shfl_xor(mx, 16, 64));
            mn = fminf(mn, __shfl_xor(mn, 32, 64));
            mx = fmaxf(mx, __shfl_xor(mx, 32, 64));
            if (lane4 == 0) { rowmn[m * 8 + w] = mn; rowmx[m * 8 + w] = mx; }
        }
    };

    // esum: c*ln(c) via v_log, 16 lanes x 7 bins per row
    auto esum = [&](int li) {
        const int* hrow = histW + rg * 100;
        float S = 0.0f;
#pragma unroll
        for (int t = 0; t < 7; ++t) {
            int b = q * 7 + t;
            if (b < 100) {
                float f = (float)hrow[b];
                float g = fmaxf(f, 1.0f);
                S = fmaf(f, __logf(g), S);
            }
        }
#pragma unroll
        for (int off = 1; off < 64; off <<= 1) S += __shfl_xor(S, off, 64);
        if (l == 0) went[w * 6 + li] = 4.0f * logf(246.0f) - S * (1.0f / 246.0f);
    };

    // ================= layer 1: K=784 streamed from HBM via reg-relay stage =================
    {
        const int srow = tid >> 4;        // 0..31
        const int skc  = (tid & 15) * 4;  // k offset within 64
        float4 xr;
        auto issueX = [&](int kt) {
            int k0 = kt * 64 + skc;
            if (k0 < K1) {                // 784 % 4 == 0 -> float4 fully valid
                xr = *(const float4*)(x + (size_t)(m0 + srow) * K1 + k0);
            } else {
                xr = float4{0.f, 0.f, 0.f, 0.f};
            }
        };
        auto writeX = [&](int buf) {
            bf16x4 h;
            h[0]=(__bf16)xr.x; h[1]=(__bf16)xr.y; h[2]=(__bf16)xr.z; h[3]=(__bf16)xr.w;
            char* st = smem + OFF_STAGE + buf * 4096;
            *(bf16x4*)(st + srow * 128 + ((skc * 2) ^ ((srow & 7) << 4))) = h;
        };
        auto lB = [&](int s, int kt, int kk) {
            const __bf16* p = W1p + (size_t)(wc + lane16) * K1PAD + kt * 64 + kk * 32 + lane4 * 8;
#pragma unroll
            for (int j = 0; j < 2; ++j)
                Bq[s][j] = *(const bf16x8*)(p + (size_t)j * 16 * K1PAD);
        };
        auto cH = [&](const char* st, int kbyte, int s) {
#pragma unroll
            for (int i = 0; i < 2; ++i) {
                int m = i * 16 + lane16;
                bf16x8 af = *(const bf16x8*)(st + m * 128 + ((kbyte + lane4 * 16) ^ ((m & 7) << 4)));
                __builtin_amdgcn_s_setprio(1);
#pragma unroll
                for (int j = 0; j < 2; ++j)
                    acc[i][j] = __builtin_amdgcn_mfma_f32_16x16x32_bf16(s ? Bq[1][j] : Bq[0][j], af, acc[i][j], 0, 0, 0);
                __builtin_amdgcn_s_setprio(0);
            }
        };

        issueX(0); writeX(0); issueX(1);
        lB(0, 0, 0);
        for (int kt = 0; kt < 13; ++kt) {
            __syncthreads();
            if (kt < 12) { writeX((kt + 1) & 1); if (kt < 11) issueX(kt + 2); }
            const char* st = smem + OFF_STAGE + (kt & 1) * 4096;
            lB(1, kt, 1);
            cH(st, 0, 0);
            if (kt < 12) lB(0, kt + 1, 0);
            cH(st, 64, 1);
        }
    }

    // bootstrap Bq for layer-2 (in flight during epilogue + barrier)
    loadBq(0, Wp, 0);
    loadBq(1, Wp, 1);
    epilogue(bpad);             // layer-1 bias; writes Hs(1) + minmax
    __syncthreads();            // Hs(1) visible; stage region dead -> hist usable

    // ================= phases p=0..4: entropy(Hs(p+1)) fused with GEMM W(p+2) =================
    for (int p = 0; p < 5; ++p) {
        const __bf16* WpP = Wp + (size_t)p * (NPAD * NPAD);
        const __bf16* WpN = WpP + NPAD * NPAD;

#pragma unroll
        for (int i = 0; i < 2; ++i)
#pragma unroll
            for (int j = 0; j < 2; ++j) acc[i][j] = f32x4{0.f, 0.f, 0.f, 0.f};

        // zero wave-private hist (400 ints)
#pragma unroll
        for (int t = 0; t < 7; ++t) { int b = t * 64 + l; if (b < 400) histW[b] = 0; }
        // per-row min/max for this wave's entropy rows
        f32x4 m4 = *(const f32x4*)(rowmn + erow * 8);
        f32x4 m5 = *(const f32x4*)(rowmn + erow * 8 + 4);
        f32x4 x4 = *(const f32x4*)(rowmx + erow * 8);
        f32x4 x5 = *(const f32x4*)(rowmx + erow * 8 + 4);
        float emn = fminf(fminf(fminf(m4[0], m4[1]), fminf(m4[2], m4[3])),
                          fminf(fminf(m5[0], m5[1]), fminf(m5[2], m5[3])));
        float emx = fmaxf(fmaxf(fmaxf(x4[0], x4[1]), fmaxf(x4[2], x4[3])),
                          fmaxf(fmaxf(x5[0], x5[1]), fmaxf(x5[2], x5[3])));
        float ers = (emx > emn) ? 100.0f / (emx - emn) : 0.0f;
        float eb  = -emn * ers;
        asm volatile("s_waitcnt lgkmcnt(0)" ::: "memory");   // hist zeros landed (wave-private)

        // fused: 8 x { 2 ds_read + 4 MFMA + B-prefetch + entropy slice (2 cols/lane) }
#pragma unroll
        for (int h = 0; h < 8; ++h) {
#pragma unroll
            for (int i = 0; i < 2; ++i) {
                int m = i * 16 + lane16;
                bf16x8 af = *(const bf16x8*)(Hb + m * 512 + ((h * 64 + lane4 * 16) ^ ((m & 7) << 4)));
                __builtin_amdgcn_s_setprio(1);
#pragma unroll
                for (int j = 0; j < 2; ++j)
                    acc[i][j] = __builtin_amdgcn_mfma_f32_16x16x32_bf16((h & 1) ? Bq[1][j] : Bq[0][j],
                                                                        af, acc[i][j], 0, 0, 0);
                __builtin_amdgcn_s_setprio(0);
            }
            // prefetch into the slot just consumed (ready at h+2)
            if (h < 6)      loadBq(h & 1, WpP, h + 2);
            else if (p < 4) loadBq(h & 1, WpN, h - 6);
            // entropy slice h: 2 cols of this lane's row
            {
                int c0 = q * 16 + h * 2;
                bf16x2 hv = *(const bf16x2*)(Hb + erow * 512 + ((c0 * 2) ^ eswz));
#pragma unroll
                for (int e = 0; e < 2; ++e) {
                    if (c0 + e < NREAL) {
                        int idx = (int)fmaf((float)hv[e], ers, eb);
                        idx = idx > BINS - 1 ? BINS - 1 : (idx < 0 ? 0 : idx);
                        atomicAdd(&histW[rg * 100 + idx], 1);
                    }
                }
            }
        }
        asm volatile("s_waitcnt lgkmcnt(0)" ::: "memory");   // own atomics done
        esum(p);

        __syncthreads();            // all waves done reading Hs(p+1)
        epilogue(bpad + (size_t)(p + 1) * NPAD);
        __syncthreads();            // Hs(p+2) + minmax visible
    }

    // ================= tail: entropy(Hs(6)) standalone =================
    {
#pragma unroll
        for (int t = 0; t < 7; ++t) { int b = t * 64 + l; if (b < 400) histW[b] = 0; }
        f32x4 m4 = *(const f32x4*)(rowmn + erow * 8);
        f32x4 m5 = *(const f32x4*)(rowmn + erow * 8 + 4);
        f32x4 x4 = *(const f32x4*)(rowmx + erow * 8);
        f32x4 x5 = *(const f32x4*)(rowmx + erow * 8 + 4);
        float emn = fminf(fminf(fminf(m4[0], m4[1]), fminf(m4[2], m4[3])),
                          fminf(fminf(m5[0], m5[1]), fminf(m5[2], m5[3])));
        float emx = fmaxf(fmaxf(fmaxf(x4[0], x4[1]), fmaxf(x4[2], x4[3])),
                          fmaxf(fmaxf(x5[0], x5[1]), fmaxf(x5[2], x5[3])));
        float ers = (emx > emn) ? 100.0f / (emx - emn) : 0.0f;
        float eb  = -emn * ers;
        asm volatile("s_waitcnt lgkmcnt(0)" ::: "memory");
#pragma unroll
        for (int h = 0; h < 8; ++h) {
            int c0 = q * 16 + h * 2;
            bf16x2 hv = *(const bf16x2*)(Hb + erow * 512 + ((c0 * 2) ^ eswz));
#pragma unroll
            for (int e = 0; e < 2; ++e) {
                if (c0 + e < NREAL) {
                    int idx = (int)fmaf((float)hv[e], ers, eb);
                    idx = idx > BINS - 1 ? BINS - 1 : (idx < 0 ? 0 : idx);
                    atomicAdd(&histW[rg * 100 + idx], 1);
                }
            }
        }
        asm volatile("s_waitcnt lgkmcnt(0)" ::: "memory");
        esum(5);
    }

    // ================= head: waves 0..1, one 16-row MFMA strip each =================
    if (w < 2) {
        f32x4 hacc = f32x4{0.f, 0.f, 0.f, 0.f};
        int row = w * 16 + lane16;
#pragma unroll
        for (int kt = 0; kt < 8; ++kt) {
            bf16x8 af = *(const bf16x8*)(Hb + row * 512 + ((kt * 64 + lane4 * 16) ^ ((row & 7) << 4)));
            bf16x8 bf = *(const bf16x8*)(W7p + (size_t)lane16 * NPAD + kt * 32 + lane4 * 8);
            hacc = __builtin_amdgcn_mfma_f32_16x16x32_bf16(af, bf, hacc, 0, 0, 0);
        }
        float bv = (lane16 < 10) ? b7[lane16] : 0.0f;
#pragma unroll
        for (int r = 0; r < 4; ++r) {
            float lg = fmaxf(hacc[r] + bv, 0.0f);
            float vm = (lane16 < 10) ? lg : -1e30f;
#pragma unroll
            for (int off = 8; off; off >>= 1) vm = fmaxf(vm, __shfl_xor(vm, off, 64));
            float ex = (lane16 < 10) ? expf(lg - vm) : 0.0f;
#pragma unroll
            for (int off = 8; off; off >>= 1) ex += __shfl_xor(ex, off, 64);
            float ls = vm + logf(ex);
            if (lane16 < 10) {
                int grow = m0 + w * 16 + lane4 * 4 + r;
                out[(size_t)grow * 10 + lane16] = lg - ls;
            }
        }
    }

    __syncthreads();
    if (tid < 6) {
        float s = 0.0f;
#pragma unroll
        for (int qq = 0; qq < 8; ++qq) s += went[qq * 6 + tid];
        partial[tid * NBLK + blockIdx.x] = s;
    }
}

// ---------------- final entropy mean (deterministic fixed-order) ----------------
__global__ __launch_bounds__(256)
void reduce_kernel(const float* __restrict__ partial, float* __restrict__ out)
{
    __shared__ float s[256];
    const int li = blockIdx.x, tid = threadIdx.x;
    float a = 0.0f;
    for (int i = tid; i < NBLK; i += 256) a += partial[li * NBLK + i];
    s[tid] = a;
    __syncthreads();
    for (int st = 128; st; st >>= 1) {
        if (tid < st) s[tid] += s[tid + st];
        __syncthreads();
    }
    if (tid == 0)
        out[(size_t)BATCH * 10 + li] = s[0] / (float)BATCH + logf((float)BINS);
}

// ---------------- launch ----------------
extern "C" void kernel_launch(void* const* d_in, const int* in_sizes, int n_in,
                              void* d_out, int out_size, void* d_ws, size_t ws_size,
                              hipStream_t stream)
{
    (void)in_sizes; (void)n_in; (void)out_size; (void)ws_size;

    const float* x  = (const float*)d_in[0];
    const float* W1 = (const float*)d_in[1];
    const float* b1 = (const float*)d_in[2];
    const float* W2 = (const float*)d_in[3];
    const float* b2 = (const float*)d_in[4];
    const float* W3 = (const float*)d_in[5];
    const float* b3 = (const float*)d_in[6];
    const float* W4 = (const float*)d_in[7];
    const float* b4 = (const float*)d_in[8];
    const float* W5 = (const float*)d_in[9];
    const float* b5 = (const float*)d_in[10];
    const float* W6 = (const float*)d_in[11];
    const float* b6 = (const float*)d_in[12];
    const float* W7 = (const float*)d_in[13];
    const float* b7 = (const float*)d_in[14];

    char* ws = (char*)d_ws;
    // ws layout (bytes):
    //   0       : W1p  256*832 bf16   = 425984
    //   425984  : Wp   5*256*256 bf16 = 655360
    //   1081344 : W7p  16*256 bf16    = 8192
    //   1089536 : bpad 6*256 f32      = 6144
    //   1095680 : partial 6*2048 f32  = 49152
    __bf16* W1p = (__bf16*)(ws);
    __bf16* Wp  = (__bf16*)(ws + 425984);
    __bf16* W7p = (__bf16*)(ws + 1081344);
    float*  bpad = (float*)(ws + 1089536);
    float*  partial = (float*)(ws + 1095680);
    float*  out = (float*)d_out;

    pad_weights<<<2134, 256, 0, stream>>>(W1, W2, W3, W4, W5, W6, W7,
                                          b1, b2, b3, b4, b5, b6,
                                          W1p, Wp, W7p, bpad);
    mega<<<NBLK, 512, 0, stream>>>(x, W1p, Wp, W7p, bpad, b7, out, partial);
    reduce_kernel<<<6, 256, 0, stream>>>(partial, out);
}